// Round 2
// baseline (257.136 us; speedup 1.0000x reference)
//
#include <hip/hip_runtime.h>

#define EDIM   4096
#define NHEAD  32
#define DHEAD  128
#define LCACHE 8191
#define LTOT   8192
#define NSPLIT 512
#define RPB    16   // rows per split

#define SCALE 0.08838834764831845f  // 1/sqrt(128)

// ---------------------------------------------------------------------------
// Kernel 1: q/k/v GEMVs (f32). grid 12288: sel = idx>>12, row = idx & 4095.
// q -> ws f32; k/v results -> row 8191 of k_new / v_new in d_out (f32).
// ---------------------------------------------------------------------------
__global__ __launch_bounds__(256) void qkv_kernel(
    const float* __restrict__ seq,
    const float* __restrict__ Wq, const float* __restrict__ bq,
    const float* __restrict__ Wk, const float* __restrict__ bk,
    const float* __restrict__ Wv, const float* __restrict__ bv,
    float* __restrict__ q_f, float* __restrict__ out)
{
    int row = blockIdx.x & 4095;
    int sel = blockIdx.x >> 12;
    const float* W = sel == 0 ? Wq : (sel == 1 ? Wk : Wv);
    const float* b = sel == 0 ? bq : (sel == 1 ? bk : bv);
    const float4* wr = (const float4*)(W + (size_t)row * EDIM);
    const float4* s4 = (const float4*)seq;
    int t = threadIdx.x;

    float sum = 0.f;
#pragma unroll
    for (int i = 0; i < 4; ++i) {
        float4 w = wr[i * 256 + t];
        float4 s = s4[i * 256 + t];
        sum += w.x * s.x + w.y * s.y + w.z * s.z + w.w * s.w;
    }
    for (int m = 32; m; m >>= 1) sum += __shfl_xor(sum, m);
    __shared__ float wsum[4];
    if ((t & 63) == 0) wsum[t >> 6] = sum;
    __syncthreads();
    if (t == 0) {
        float total = wsum[0] + wsum[1] + wsum[2] + wsum[3] + b[row];
        if (sel == 0)      q_f[row] = total;
        else if (sel == 1) out[(size_t)EDIM * (1 + LCACHE) + row] = total;
        else               out[(size_t)EDIM * (1 + LTOT + LCACHE) + row] = total;
    }
}

// ---------------------------------------------------------------------------
// Kernel 2: fused KV-copy + flash-decode partials.
// grid NSPLIT=512, block 256.  Thread t: head h=t>>3, sublane sl=t&7,
// owns global cols [16t, 16t+16) = head h dims [16*sl, 16*sl+16).
// K pass: read kc row (or new row from d_out), write k_new, per-head dot.
// local softmax over RPB rows; V pass: read/write v + weighted accumulate.
// ---------------------------------------------------------------------------
__global__ __launch_bounds__(256) void fused_copy_attn(
    const float* __restrict__ kc, const float* __restrict__ vc,
    const float* __restrict__ q_f, float* __restrict__ out,
    float* __restrict__ pm, float* __restrict__ pl, float* __restrict__ po)
{
    int s  = blockIdx.x;
    int t  = threadIdx.x;
    int h  = t >> 3;
    int sl = t & 7;
    int r0 = s * RPB;

    __shared__ float sc[NHEAD][RPB + 1];

    float* knew = out + EDIM;
    float* vnew = out + (size_t)EDIM * (1 + LTOT);

    // q fragment (16 floats, prescaled)
    float qr[16];
    {
        const float4* q4 = (const float4*)q_f;
#pragma unroll
        for (int j = 0; j < 4; ++j) {
            float4 v = q4[t * 4 + j];
            qr[j * 4 + 0] = v.x * SCALE; qr[j * 4 + 1] = v.y * SCALE;
            qr[j * 4 + 2] = v.z * SCALE; qr[j * 4 + 3] = v.w * SCALE;
        }
    }

    // ---- K pass ----
    for (int i = 0; i < RPB; ++i) {
        int row = r0 + i;
        const float4* src = (row < LCACHE)
            ? (const float4*)(kc + (size_t)row * EDIM)
            : (const float4*)(knew + (size_t)row * EDIM);
        float4 a[4];
#pragma unroll
        for (int j = 0; j < 4; ++j) a[j] = src[t * 4 + j];
        if (row < LCACHE) {
            float4* dst = (float4*)(knew + (size_t)row * EDIM);
#pragma unroll
            for (int j = 0; j < 4; ++j) dst[t * 4 + j] = a[j];
        }
        float d = 0.f;
#pragma unroll
        for (int j = 0; j < 4; ++j)
            d += a[j].x * qr[j*4+0] + a[j].y * qr[j*4+1] +
                 a[j].z * qr[j*4+2] + a[j].w * qr[j*4+3];
        d += __shfl_xor(d, 1); d += __shfl_xor(d, 2); d += __shfl_xor(d, 4);
        if (sl == 0) sc[h][i] = d;
    }
    __syncthreads();

    // ---- local softmax per head (8 lanes per head, 2 rows each) ----
    float v0 = sc[h][sl], v1 = sc[h][sl + 8];
    float m = fmaxf(v0, v1);
    m = fmaxf(m, __shfl_xor(m, 1));
    m = fmaxf(m, __shfl_xor(m, 2));
    m = fmaxf(m, __shfl_xor(m, 4));
    float p0 = __expf(v0 - m), p1 = __expf(v1 - m);
    sc[h][sl] = p0; sc[h][sl + 8] = p1;
    float l = p0 + p1;
    l += __shfl_xor(l, 1); l += __shfl_xor(l, 2); l += __shfl_xor(l, 4);
    if (sl == 0) { pm[s * NHEAD + h] = m; pl[s * NHEAD + h] = l; }
    __syncthreads();

    // ---- V pass ----
    float acc[16];
#pragma unroll
    for (int e = 0; e < 16; ++e) acc[e] = 0.f;
    for (int i = 0; i < RPB; ++i) {
        int row = r0 + i;
        const float4* src = (row < LCACHE)
            ? (const float4*)(vc + (size_t)row * EDIM)
            : (const float4*)(vnew + (size_t)row * EDIM);
        float4 a[4];
#pragma unroll
        for (int j = 0; j < 4; ++j) a[j] = src[t * 4 + j];
        if (row < LCACHE) {
            float4* dst = (float4*)(vnew + (size_t)row * EDIM);
#pragma unroll
            for (int j = 0; j < 4; ++j) dst[t * 4 + j] = a[j];
        }
        float w = sc[h][i];
#pragma unroll
        for (int j = 0; j < 4; ++j) {
            acc[j*4+0] += w * a[j].x; acc[j*4+1] += w * a[j].y;
            acc[j*4+2] += w * a[j].z; acc[j*4+3] += w * a[j].w;
        }
    }
    float4* pd = (float4*)(po + ((size_t)s * NHEAD + h) * DHEAD + sl * 16);
#pragma unroll
    for (int j = 0; j < 4; ++j) {
        float4 v; v.x = acc[j*4+0]; v.y = acc[j*4+1];
        v.z = acc[j*4+2]; v.w = acc[j*4+3];
        pd[j] = v;
    }
}

// ---------------------------------------------------------------------------
// Kernel 3: combine split partials -> attn vector (f32, ws).  grid 32 heads.
// ---------------------------------------------------------------------------
__global__ __launch_bounds__(128) void combine_kernel(
    const float* __restrict__ pm, const float* __restrict__ pl,
    const float* __restrict__ po, float* __restrict__ attn_f)
{
    int h = blockIdx.x;
    int t = threadIdx.x;
    __shared__ float sm[NSPLIT], sw[NSPLIT];
    for (int i = t; i < NSPLIT; i += 128) {
        sm[i] = pm[(size_t)i * NHEAD + h];
        sw[i] = pl[(size_t)i * NHEAD + h];
    }
    __syncthreads();
    float M = -1e30f;
    for (int i = 0; i < NSPLIT; ++i) M = fmaxf(M, sm[i]);
    float L = 0.f, o = 0.f;
#pragma unroll 4
    for (int i = 0; i < NSPLIT; ++i) {
        float w = __expf(sm[i] - M);
        L += sw[i] * w;
        o += w * po[((size_t)i * NHEAD + h) * DHEAD + t];
    }
    attn_f[h * DHEAD + t] = o / L;
}

// ---------------------------------------------------------------------------
// Kernel 4: output projection out[row] = attn . Wq[row] + bq[row]  (f32)
// ---------------------------------------------------------------------------
__global__ __launch_bounds__(256) void proj_kernel(
    const float* __restrict__ attn_f, const float* __restrict__ Wq,
    const float* __restrict__ bq, float* __restrict__ out)
{
    int row = blockIdx.x;
    const float4* wr = (const float4*)(Wq + (size_t)row * EDIM);
    const float4* a4 = (const float4*)attn_f;
    int t = threadIdx.x;
    float sum = 0.f;
#pragma unroll
    for (int i = 0; i < 4; ++i) {
        float4 w = wr[i * 256 + t];
        float4 a = a4[i * 256 + t];
        sum += w.x * a.x + w.y * a.y + w.z * a.z + w.w * a.w;
    }
    for (int m = 32; m; m >>= 1) sum += __shfl_xor(sum, m);
    __shared__ float wsum[4];
    if ((t & 63) == 0) wsum[t >> 6] = sum;
    __syncthreads();
    if (t == 0)
        out[row] = wsum[0] + wsum[1] + wsum[2] + wsum[3] + bq[row];
}

// ---------------------------------------------------------------------------
extern "C" void kernel_launch(void* const* d_in, const int* in_sizes, int n_in,
                              void* d_out, int out_size, void* d_ws, size_t ws_size,
                              hipStream_t stream)
{
    const float* seq = (const float*)d_in[0];
    const float* kc  = (const float*)d_in[1];
    const float* vc  = (const float*)d_in[2];
    const float* Wq  = (const float*)d_in[3];
    const float* bq  = (const float*)d_in[4];
    const float* Wk  = (const float*)d_in[5];
    const float* bk  = (const float*)d_in[6];
    const float* Wv  = (const float*)d_in[7];
    const float* bv  = (const float*)d_in[8];
    float* out = (float*)d_out;

    float* wsf    = (float*)d_ws;
    float* q_f    = wsf;                        // 4096
    float* attn_f = wsf + 4096;                 // 4096
    float* pm     = wsf + 8192;                 // 512*32
    float* pl     = pm + NSPLIT * NHEAD;        // 512*32
    float* po     = pl + NSPLIT * NHEAD;        // 512*32*128 = 2M floats

    hipLaunchKernelGGL(qkv_kernel, dim3(3 * 4096), dim3(256), 0, stream,
                       seq, Wq, bq, Wk, bk, Wv, bv, q_f, out);
    hipLaunchKernelGGL(fused_copy_attn, dim3(NSPLIT), dim3(256), 0, stream,
                       kc, vc, q_f, out, pm, pl, po);
    hipLaunchKernelGGL(combine_kernel, dim3(NHEAD), dim3(128), 0, stream,
                       pm, pl, po, attn_f);
    hipLaunchKernelGGL(proj_kernel, dim3(4096), dim3(256), 0, stream,
                       attn_f, Wq, bq, out);
}